// Round 9
// baseline (379.889 us; speedup 1.0000x reference)
//
#include <hip/hip_runtime.h>
#include <type_traits>

// GraphSAGE 2-layer, N=100k, C 128->128->64, E=1.6M, fp32 in/out.
// R9/R10: latency-optimized quarter-per-node aggregation.
// R11-R15: fused-panel persistent GEMM (reg-B pin) — 266us baseline.
// R16: cooperative mega-kernel FAILED (coop launch incompatible with graph
//      capture; outputs never written). Reverted.
// R17: gap reduction without grid.sync — dispatches 10 -> 7:
//  * wprep deleted: B fragments direct-loaded from fp32 W (in-register
//    transpose + bf16 cast; index math identical to wprep path).
//  * memset+bucketTotal deleted: k_btop column-sums blockHist.
//  * k_bfill + k_agg128 FUSED per bucket: fill rowptr/col slice (LDS copy
//    of col), then aggregate the bucket's 256 nodes in the same block.

constexpr int K = 128;
constexpr int EB = 4096;    // edges per partition block
constexpr int COLCAP = 6144;  // LDS col capacity per bucket (mean 4092, +32 sigma)

typedef __bf16 bf16x2 __attribute__((ext_vector_type(2)));
typedef __bf16 bf16x4 __attribute__((ext_vector_type(4)));
typedef __bf16 bf16x8 __attribute__((ext_vector_type(8)));
typedef float f32x4 __attribute__((ext_vector_type(4)));
typedef float f32x2 __attribute__((ext_vector_type(2)));

// ---------------- fp8 e4m3 conversion ----------------

__device__ __forceinline__ unsigned char to_fp8(float v) {
#if __has_builtin(__builtin_amdgcn_cvt_pk_fp8_f32)
  int p = __builtin_amdgcn_cvt_pk_fp8_f32(v, v, 0, false);
  return (unsigned char)(p & 0xff);
#else
  unsigned u = __builtin_bit_cast(unsigned, v);
  unsigned s = (u >> 24) & 0x80u;
  float a = fabsf(v);
  if (a > 448.f) a = 448.f;
  unsigned bits;
  if (a < 0.015625f) {
    bits = (unsigned)(a * 512.f + 0.5f);
  } else {
    unsigned b = __builtin_bit_cast(unsigned, a);
    b += ((b >> 20) & 1) + 0x0007FFFF;
    unsigned e = (b >> 23) - 120;
    bits = (e << 3) | ((b >> 20) & 7);
    if (bits > 0x7E) bits = 0x7E;
  }
  return (unsigned char)(s | bits);
#endif
}

__device__ __forceinline__ f32x2 from_fp8x2(unsigned short u) {
#if __has_builtin(__builtin_amdgcn_cvt_pk_f32_fp8)
  return __builtin_amdgcn_cvt_pk_f32_fp8((int)u, false);
#else
  f32x2 r;
  unsigned b0 = u & 0xff, b1 = (u >> 8) & 0xff;
  unsigned e0 = (b0 >> 3) & 15, m0 = b0 & 7;
  unsigned e1 = (b1 >> 3) & 15, m1 = b1 & 7;
  float v0 = e0 ? __builtin_bit_cast(float, ((e0 + 120) << 23) | (m0 << 20))
              : (float)m0 * 0.001953125f;
  float v1 = e1 ? __builtin_bit_cast(float, ((e1 + 120) << 23) | (m1 << 20))
              : (float)m1 * 0.001953125f;
  r[0] = (b0 & 0x80) ? -v0 : v0;
  r[1] = (b1 & 0x80) ? -v1 : v1;
  return r;
#endif
}

__device__ __forceinline__ f32x2 fp8x2_lo(unsigned v) {
#if __has_builtin(__builtin_amdgcn_cvt_pk_f32_fp8)
  return __builtin_amdgcn_cvt_pk_f32_fp8((int)v, false);
#else
  return from_fp8x2((unsigned short)(v & 0xffffu));
#endif
}

__device__ __forceinline__ f32x2 fp8x2_hi(unsigned v) {
#if __has_builtin(__builtin_amdgcn_cvt_pk_f32_fp8)
  return __builtin_amdgcn_cvt_pk_f32_fp8((int)v, true);
#else
  return from_fp8x2((unsigned short)(v >> 16));
#endif
}

// ---------------- bucketed CSR build ----------------

__global__ __launch_bounds__(256) void k_bhist(const int* __restrict__ dst,
                                               int* __restrict__ blockHist,
                                               int E, int n, int nB) {
  extern __shared__ int hist[];
  for (int i = threadIdx.x; i < nB; i += 256) hist[i] = 0;
  __syncthreads();
  int base = blockIdx.x * EB, end = min(base + EB, E);
  for (int e = base + threadIdx.x; e < end; e += 256) {
    int d = dst[e];
    if ((unsigned)d < (unsigned)n) atomicAdd(&hist[d >> 8], 1);
  }
  __syncthreads();
  for (int i = threadIdx.x; i < nB; i += 256)
    blockHist[(long)blockIdx.x * nB + i] = hist[i];
}

// Bucket totals = column sums of blockHist (no separate memset/atomics),
// then exclusive scan -> bucketBase/bucketCursor.
__global__ __launch_bounds__(512) void k_btop(const int* __restrict__ blockHist,
                                              int* __restrict__ bucketBase,
                                              int* __restrict__ bucketCursor,
                                              int nB, int nblk) {
  __shared__ int sh[512];
  int t = threadIdx.x;
  int s = 0;
  if (t < nB)
    for (int b = 0; b < nblk; ++b) s += blockHist[(long)b * nB + t];
  sh[t] = s;
  __syncthreads();
  for (int off = 1; off < 512; off <<= 1) {
    int v = (t >= off) ? sh[t - off] : 0;
    __syncthreads();
    sh[t] += v;
    __syncthreads();
  }
  if (t < nB) {
    int base = sh[t] - s;
    bucketBase[t] = base;
    bucketCursor[t] = base;
    if (t == nB - 1) bucketBase[nB] = sh[t];
  }
}

__global__ __launch_bounds__(256) void k_bscatter(const int* __restrict__ src,
                                                  const int* __restrict__ dst,
                                                  const int* __restrict__ blockHist,
                                                  int* __restrict__ bucketCursor,
                                                  unsigned* __restrict__ recs,
                                                  int E, int n, int nB) {
  extern __shared__ int cur[];
  for (int i = threadIdx.x; i < nB; i += 256) {
    int c = blockHist[(long)blockIdx.x * nB + i];
    cur[i] = c ? atomicAdd(&bucketCursor[i], c) : 0;
  }
  __syncthreads();
  int base = blockIdx.x * EB, end = min(base + EB, E);
  for (int e = base + threadIdx.x; e < end; e += 256) {
    int d = dst[e];
    if ((unsigned)d < (unsigned)n) {
      int s = min(max(src[e], 0), n - 1);
      int pos = atomicAdd(&cur[d >> 8], 1);
      recs[pos] = ((unsigned)s << 8) | (unsigned)(d & 255);
    }
  }
}

// ---------------- fused bucket fill + layer-1 aggregation ----------------
// Per block = one bucket of 256 nodes: (1) build rowptr slice + col slice
// (global for layer 2, LDS copy for this kernel), (2) aggregate the
// bucket's nodes with R10's quarter-per-node scheme, indices from LDS.

template <bool RELU>
__global__ __launch_bounds__(256) void k_bfill_agg(
    const unsigned* __restrict__ recs, const int* __restrict__ bucketBase,
    int* __restrict__ rowptr, int* __restrict__ col,
    const unsigned char* __restrict__ Y, const __bf16* __restrict__ XR,
    const float* __restrict__ bias, __bf16* __restrict__ out, int n) {
  __shared__ int degl[256];
  __shared__ int incl[256];
  __shared__ int rp[257];
  __shared__ int cur[256];
  __shared__ int colLds[COLCAP];
  int b = blockIdx.x, t = threadIdx.x;
  int rbeg = bucketBase[b], rend = bucketBase[b + 1];
  bool useLds = (rend - rbeg) <= COLCAP;

  degl[t] = 0;
  __syncthreads();
  for (int i = rbeg + t; i < rend; i += 256)
    atomicAdd(&degl[recs[i] & 255], 1);
  __syncthreads();
  incl[t] = degl[t];
  __syncthreads();
  for (int off = 1; off < 256; off <<= 1) {
    int v = (t >= off) ? incl[t - off] : 0;
    __syncthreads();
    incl[t] += v;
    __syncthreads();
  }
  int excl = incl[t] - degl[t];
  rp[t] = rbeg + excl;
  if (t == 255) rp[256] = rend;
  int node = b * 256 + t;
  if (node <= n) rowptr[node] = rbeg + excl;
  cur[t] = rbeg + excl;
  __syncthreads();
  for (int i = rbeg + t; i < rend; i += 256) {
    unsigned r = recs[i];
    int pos = atomicAdd(&cur[r & 255], 1);
    int sv = (int)(r >> 8);
    col[pos] = sv;                              // global (layer-2 agg)
    if (useLds) colLds[pos - rbeg] = sv;        // LDS (this kernel)
  }
  __syncthreads();

  // ---- aggregation: 16 passes x 16 nodes (quarter-per-node) ----
  int wave = t >> 6, lane = t & 63;
  int quarter = lane >> 4, l = lane & 15;
  int sb = lane & 48;
  int co = l * 8;
  const unsigned char* Yc = Y + co;

  for (int pass = 0; pass < 16; ++pass) {
    int nl = pass * 16 + wave * 4 + quarter;  // node-local 0..255
    int nn = b * 256 + nl;
    bool valid = nn < n;
    int beg = rp[nl], end = rp[nl + 1];

    f32x2 av0 = {0.f, 0.f}, av1 = {0.f, 0.f}, av2 = {0.f, 0.f}, av3 = {0.f, 0.f};

    for (int base = beg; base < end; base += 16) {
      int cnt = min(end - base, 16);
      int idx = 0;
      if (l < cnt)
        idx = useLds ? colLds[base - rbeg + l] : col[base + l];
      int j = 0;
      for (; j + 3 < cnt; j += 4) {
        long s0 = (unsigned)__shfl(idx, sb + j);
        long s1 = (unsigned)__shfl(idx, sb + j + 1);
        long s2 = (unsigned)__shfl(idx, sb + j + 2);
        long s3 = (unsigned)__shfl(idx, sb + j + 3);
        uint2 v0 = *(const uint2*)(Yc + s0 * 128);
        uint2 v1 = *(const uint2*)(Yc + s1 * 128);
        uint2 v2 = *(const uint2*)(Yc + s2 * 128);
        uint2 v3 = *(const uint2*)(Yc + s3 * 128);
        av0 += fp8x2_lo(v0.x); av1 += fp8x2_hi(v0.x);
        av2 += fp8x2_lo(v0.y); av3 += fp8x2_hi(v0.y);
        av0 += fp8x2_lo(v1.x); av1 += fp8x2_hi(v1.x);
        av2 += fp8x2_lo(v1.y); av3 += fp8x2_hi(v1.y);
        av0 += fp8x2_lo(v2.x); av1 += fp8x2_hi(v2.x);
        av2 += fp8x2_lo(v2.y); av3 += fp8x2_hi(v2.y);
        av0 += fp8x2_lo(v3.x); av1 += fp8x2_hi(v3.x);
        av2 += fp8x2_lo(v3.y); av3 += fp8x2_hi(v3.y);
      }
      for (; j < cnt; ++j) {
        long s = (unsigned)__shfl(idx, sb + j);
        uint2 v = *(const uint2*)(Yc + s * 128);
        av0 += fp8x2_lo(v.x); av1 += fp8x2_hi(v.x);
        av2 += fp8x2_lo(v.y); av3 += fp8x2_hi(v.y);
      }
    }

    if (valid) {
      float inv = 1.f / (float)max(end - beg, 1);
      bf16x8 xv = *(const bf16x8*)(XR + (long)nn * 128 + co);
      f32x4 b0 = *(const f32x4*)(bias + co);
      f32x4 b1 = *(const f32x4*)(bias + co + 4);
      float r0 = av0[0] * inv + (float)xv[0] + b0[0];
      float r1 = av0[1] * inv + (float)xv[1] + b0[1];
      float r2 = av1[0] * inv + (float)xv[2] + b0[2];
      float r3 = av1[1] * inv + (float)xv[3] + b0[3];
      float r4 = av2[0] * inv + (float)xv[4] + b1[0];
      float r5 = av2[1] * inv + (float)xv[5] + b1[1];
      float r6 = av3[0] * inv + (float)xv[6] + b1[2];
      float r7 = av3[1] * inv + (float)xv[7] + b1[3];
      if (RELU) {
        r0 = fmaxf(r0, 0.f); r1 = fmaxf(r1, 0.f);
        r2 = fmaxf(r2, 0.f); r3 = fmaxf(r3, 0.f);
        r4 = fmaxf(r4, 0.f); r5 = fmaxf(r5, 0.f);
        r6 = fmaxf(r6, 0.f); r7 = fmaxf(r7, 0.f);
      }
      bf16x8 o;
      o[0] = (__bf16)r0; o[1] = (__bf16)r1; o[2] = (__bf16)r2; o[3] = (__bf16)r3;
      o[4] = (__bf16)r4; o[5] = (__bf16)r5; o[6] = (__bf16)r6; o[7] = (__bf16)r7;
      *(bf16x8*)(out + (long)nn * 128 + co) = o;
    }
  }
}

// ---------------- persistent fused-panel GEMM (direct fp32 B) ----------------
// Block = 64-row tiles (grid-stride), 512 threads (8 waves). Wave w:
// panel = w>>2 (Wl->fp8 / Wr->bf16), col strip (w&3)*16*NI, NI=COLS/64.
// B fragments: in-register transposing load from fp32 W + bf16 cast
// (numerically identical to the old wprep path), pinned once per block.
// Double-buffered LDS A with register prefetch of tile t+1.

template <int COLS, typename TIN>
__global__ __launch_bounds__(512, 4) void k_gemm_fused(const TIN* __restrict__ X,
                                                       const float* __restrict__ Wa,
                                                       const float* __restrict__ Wb,
                                                       unsigned char* __restrict__ outA,
                                                       __bf16* __restrict__ outB,
                                                       int nrows, int ntiles) {
  constexpr int LD = 136;
  constexpr int NI = COLS / 64;
  constexpr bool FP32IN = std::is_same_v<TIN, float>;
  __shared__ __bf16 As[2][64 * LD];

  int tid = threadIdx.x;
  int w = tid >> 6, lane = tid & 63;
  int m = lane & 15, quad = lane >> 4;
  int panel = w >> 2;
  int wcol = (w & 3) * (16 * NI);
  const float* Wsrc = panel ? Wb : Wa;

  bf16x8 bq[4][NI];
#pragma unroll
  for (int kc = 0; kc < 4; ++kc)
#pragma unroll
    for (int ni = 0; ni < NI; ++ni)
#pragma unroll
      for (int e = 0; e < 8; ++e)
        bq[kc][ni][e] = (__bf16)Wsrc[(kc * 32 + quad * 8 + e) * COLS + (wcol + ni * 16 + m)];

  float4 ra[4];
  bf16x8 rb[2];

  auto load_tile = [&](int t) {
    long row0 = (long)t * 64;
    if constexpr (FP32IN) {
#pragma unroll
      for (int it = 0; it < 4; ++it) {
        int i = tid + it * 512;
        int r = i >> 5, c4 = (i & 31) << 2;
        long row = row0 + r;
        float4 v = make_float4(0.f, 0.f, 0.f, 0.f);
        if (row < nrows) v = *(const float4*)(X + row * K + c4);
        ra[it] = v;
      }
    } else {
#pragma unroll
      for (int it = 0; it < 2; ++it) {
        int i = tid + it * 512;
        int r = i >> 4, c8 = (i & 15) << 3;
        long row = row0 + r;
        bf16x8 v = {};
        if (row < nrows) v = *(const bf16x8*)(X + row * K + c8);
        rb[it] = v;
      }
    }
  };

  auto write_tile = [&](int buf) {
    if constexpr (FP32IN) {
#pragma unroll
      for (int it = 0; it < 4; ++it) {
        int i = tid + it * 512;
        int r = i >> 5, c4 = (i & 31) << 2;
        bf16x4 bb;
        bb[0] = (__bf16)ra[it].x; bb[1] = (__bf16)ra[it].y;
        bb[2] = (__bf16)ra[it].z; bb[3] = (__bf16)ra[it].w;
        *(bf16x4*)&As[buf][r * LD + c4] = bb;
      }
    } else {
#pragma unroll
      for (int it = 0; it < 2; ++it) {
        int i = tid + it * 512;
        int r = i >> 4, c8 = (i & 15) << 3;
        *(bf16x8*)&As[buf][r * LD + c8] = rb[it];
      }
    }
  };

  int t = (int)blockIdx.x;
  int stride = (int)gridDim.x;
  if (t < ntiles) load_tile(t);

#pragma unroll
  for (int kc = 0; kc < 4; ++kc)
#pragma unroll
    for (int ni = 0; ni < NI; ++ni)
      asm volatile("" :: "v"(bq[kc][ni]));

  int buf = 0;
  while (t < ntiles) {
    write_tile(buf);
    __syncthreads();
    int tn = t + stride;
    if (tn < ntiles) load_tile(tn);  // prefetch under compute

    f32x4 acc[4][NI];
#pragma unroll
    for (int mi = 0; mi < 4; ++mi)
#pragma unroll
      for (int ni = 0; ni < NI; ++ni) acc[mi][ni] = (f32x4){0.f, 0.f, 0.f, 0.f};

#pragma unroll
    for (int kc = 0; kc < 4; ++kc) {
      int ko = kc * 32 + quad * 8;
      bf16x8 af[4];
#pragma unroll
      for (int mi = 0; mi < 4; ++mi)
        af[mi] = *(const bf16x8*)&As[buf][(mi * 16 + m) * LD + ko];
#pragma unroll
      for (int mi = 0; mi < 4; ++mi)
#pragma unroll
        for (int ni = 0; ni < NI; ++ni)
          acc[mi][ni] = __builtin_amdgcn_mfma_f32_16x16x32_bf16(af[mi], bq[kc][ni], acc[mi][ni], 0, 0, 0);
    }

    long row0 = (long)t * 64;
#pragma unroll
    for (int mi = 0; mi < 4; ++mi) {
#pragma unroll
      for (int r = 0; r < 4; ++r) {
        long grow = row0 + mi * 16 + quad * 4 + r;
        if (grow < nrows) {
#pragma unroll
          for (int ni = 0; ni < NI; ++ni) {
            long idx = grow * COLS + wcol + ni * 16 + m;
            float v = acc[mi][ni][r];
            if (panel == 0) outA[idx] = to_fp8(v);
            else            outB[idx] = (__bf16)v;
          }
        }
      }
    }
    t = tn;
    buf ^= 1;
  }
}

// ---------------- layer-2 aggregation (unchanged R10 structure) ----------------

__global__ __launch_bounds__(256) void k_agg64(const unsigned char* __restrict__ Y,
                                               const __bf16* __restrict__ XR,
                                               const float* __restrict__ bias,
                                               const int* __restrict__ rowptr,
                                               const int* __restrict__ col,
                                               float* __restrict__ out, int nnodes) {
  int wave = threadIdx.x >> 6, lane = threadIdx.x & 63;
  int quarter = lane >> 4, l = lane & 15;
  int sb = lane & 48;
  int n = blockIdx.x * 16 + wave * 4 + quarter;
  bool valid = n < nnodes;
  int beg = 0, end = 0;
  if (valid) {
    beg = rowptr[n];
    end = rowptr[n + 1];
  }
  int co = l * 4;
  const unsigned char* Yc = Y + co;

  f32x2 av0 = {0.f, 0.f}, av1 = {0.f, 0.f};

  for (int base = beg; base < end; base += 16) {
    int cnt = min(end - base, 16);
    int idx = (l < cnt) ? col[base + l] : 0;
    int j = 0;
    for (; j + 3 < cnt; j += 4) {
      long s0 = (unsigned)__shfl(idx, sb + j);
      long s1 = (unsigned)__shfl(idx, sb + j + 1);
      long s2 = (unsigned)__shfl(idx, sb + j + 2);
      long s3 = (unsigned)__shfl(idx, sb + j + 3);
      unsigned v0 = *(const unsigned*)(Yc + s0 * 64);
      unsigned v1 = *(const unsigned*)(Yc + s1 * 64);
      unsigned v2 = *(const unsigned*)(Yc + s2 * 64);
      unsigned v3 = *(const unsigned*)(Yc + s3 * 64);
      av0 += fp8x2_lo(v0); av1 += fp8x2_hi(v0);
      av0 += fp8x2_lo(v1); av1 += fp8x2_hi(v1);
      av0 += fp8x2_lo(v2); av1 += fp8x2_hi(v2);
      av0 += fp8x2_lo(v3); av1 += fp8x2_hi(v3);
    }
    for (; j < cnt; ++j) {
      long s = (unsigned)__shfl(idx, sb + j);
      unsigned v = *(const unsigned*)(Yc + s * 64);
      av0 += fp8x2_lo(v); av1 += fp8x2_hi(v);
    }
  }

  if (valid) {
    float inv = 1.f / (float)max(end - beg, 1);
    bf16x4 xv = *(const bf16x4*)(XR + (long)n * 64 + co);
    f32x4 bv = *(const f32x4*)(bias + co);
    f32x4 r;
    r[0] = av0[0] * inv + (float)xv[0] + bv[0];
    r[1] = av0[1] * inv + (float)xv[1] + bv[1];
    r[2] = av1[0] * inv + (float)xv[2] + bv[2];
    r[3] = av1[1] * inv + (float)xv[3] + bv[3];
    *(f32x4*)(out + (long)n * 64 + co) = r;
  }
}

// ---------------- launch ----------------

extern "C" void kernel_launch(void* const* d_in, const int* in_sizes, int n_in,
                              void* d_out, int out_size, void* d_ws, size_t ws_size,
                              hipStream_t stream) {
  const float* x   = (const float*)d_in[0];
  const int*   ei  = (const int*)d_in[1];
  const float* W1l = (const float*)d_in[2];
  const float* W1r = (const float*)d_in[3];
  const float* b1  = (const float*)d_in[4];
  const float* W2l = (const float*)d_in[5];
  const float* W2r = (const float*)d_in[6];
  const float* b2  = (const float*)d_in[7];
  float* out = (float*)d_out;

  int N = in_sizes[0] / K;   // 100000
  int E = in_sizes[1] / 2;   // 1600000
  const int* src = ei;
  const int* dst = ei + E;

  int nB = (N + 255) >> 8;          // 391 buckets of 256 nodes
  int nblk = (E + EB - 1) / EB;     // 391 partition blocks

  char* ws = (char*)d_ws;
  size_t off = 0;
  auto alloc = [&](size_t bytes) {
    void* p = ws + off;
    off = (off + bytes + 255) & ~(size_t)255;
    return p;
  };
  int*      rowptr       = (int*)alloc(((size_t)N + 2) * 4);
  int*      col          = (int*)alloc((size_t)E * 4);
  int*      blockHist    = (int*)alloc((size_t)nblk * nB * 4);
  int*      bucketBase   = (int*)alloc(((size_t)nB + 1) * 4);
  int*      bucketCursor = (int*)alloc((size_t)nB * 4);
  unsigned* recs         = (unsigned*)alloc((size_t)E * 4);
  unsigned char* y1      = (unsigned char*)alloc((size_t)N * 128);  // fp8
  __bf16*   xr           = (__bf16*)alloc((size_t)N * 128 * 2);
  __bf16*   h            = (__bf16*)alloc((size_t)N * 128 * 2);
  unsigned char* y2 = y1;  // layer-1 gather buffer dead after bfill_agg; reuse
  __bf16*   hr = xr;

  int ntiles = (N + 63) / 64;
  int gpers = ntiles < 512 ? ntiles : 512;

  // CSR build (3 dispatches; totals derived in btop, no memset)
  k_bhist<<<nblk, 256, nB * 4, stream>>>(dst, blockHist, E, N, nB);
  k_btop<<<1, 512, 0, stream>>>(blockHist, bucketBase, bucketCursor, nB, nblk);
  k_bscatter<<<nblk, 256, nB * 4, stream>>>(src, dst, blockHist, bucketCursor, recs, E, N, nB);

  // layer 1: y1 = fp8(x@W1l), xr = bf16(x@W1r)
  k_gemm_fused<128, float><<<gpers, 512, 0, stream>>>(x, W1l, W1r, y1, xr, N, ntiles);

  // fused: fill rowptr/col per bucket + h = relu(mean(y1) + xr + b1)
  k_bfill_agg<true><<<nB, 256, 0, stream>>>(recs, bucketBase, rowptr, col, y1, xr, b1, h, N);

  // layer 2: y2 = fp8(h@W2l), hr = bf16(h@W2r)
  k_gemm_fused<64, __bf16><<<gpers, 512, 0, stream>>>(h, W2l, W2r, y2, hr, N, ntiles);

  // out = mean_gather(y2) + hr + b2
  k_agg64<<<(N + 15) / 16, 256, 0, stream>>>(y2, hr, b2, rowptr, col, out, N);
}

// Round 10
// 297.558 us; speedup vs baseline: 1.2767x; 1.2767x over previous
//
#include <hip/hip_runtime.h>
#include <type_traits>

// GraphSAGE 2-layer, N=100k, C 128->128->64, E=1.6M, fp32 in/out.
// R9/R10: latency-optimized quarter-per-node aggregation.
// R11-R15: fused-panel persistent GEMM (reg-B pin) — 266us baseline.
// R16: cooperative mega-kernel FAILED (coop launch vs graph capture).
// R17: wprep deleted (direct fp32-B load), bfill+agg128 fused  — BOTH OK;
//      but btop-as-column-sum REGRESSED (98us single-block latency chain).
// R18: restore memset+atomic bucketTotal path (btop = 1 load/thread scan);
//      keep R17's validated wins. 8 dispatches.

constexpr int K = 128;
constexpr int EB = 4096;    // edges per partition block
constexpr int COLCAP = 6144;  // LDS col capacity per bucket

typedef __bf16 bf16x2 __attribute__((ext_vector_type(2)));
typedef __bf16 bf16x4 __attribute__((ext_vector_type(4)));
typedef __bf16 bf16x8 __attribute__((ext_vector_type(8)));
typedef float f32x4 __attribute__((ext_vector_type(4)));
typedef float f32x2 __attribute__((ext_vector_type(2)));

// ---------------- fp8 e4m3 conversion ----------------

__device__ __forceinline__ unsigned char to_fp8(float v) {
#if __has_builtin(__builtin_amdgcn_cvt_pk_fp8_f32)
  int p = __builtin_amdgcn_cvt_pk_fp8_f32(v, v, 0, false);
  return (unsigned char)(p & 0xff);
#else
  unsigned u = __builtin_bit_cast(unsigned, v);
  unsigned s = (u >> 24) & 0x80u;
  float a = fabsf(v);
  if (a > 448.f) a = 448.f;
  unsigned bits;
  if (a < 0.015625f) {
    bits = (unsigned)(a * 512.f + 0.5f);
  } else {
    unsigned b = __builtin_bit_cast(unsigned, a);
    b += ((b >> 20) & 1) + 0x0007FFFF;
    unsigned e = (b >> 23) - 120;
    bits = (e << 3) | ((b >> 20) & 7);
    if (bits > 0x7E) bits = 0x7E;
  }
  return (unsigned char)(s | bits);
#endif
}

__device__ __forceinline__ f32x2 from_fp8x2(unsigned short u) {
#if __has_builtin(__builtin_amdgcn_cvt_pk_f32_fp8)
  return __builtin_amdgcn_cvt_pk_f32_fp8((int)u, false);
#else
  f32x2 r;
  unsigned b0 = u & 0xff, b1 = (u >> 8) & 0xff;
  unsigned e0 = (b0 >> 3) & 15, m0 = b0 & 7;
  unsigned e1 = (b1 >> 3) & 15, m1 = b1 & 7;
  float v0 = e0 ? __builtin_bit_cast(float, ((e0 + 120) << 23) | (m0 << 20))
              : (float)m0 * 0.001953125f;
  float v1 = e1 ? __builtin_bit_cast(float, ((e1 + 120) << 23) | (m1 << 20))
              : (float)m1 * 0.001953125f;
  r[0] = (b0 & 0x80) ? -v0 : v0;
  r[1] = (b1 & 0x80) ? -v1 : v1;
  return r;
#endif
}

__device__ __forceinline__ f32x2 fp8x2_lo(unsigned v) {
#if __has_builtin(__builtin_amdgcn_cvt_pk_f32_fp8)
  return __builtin_amdgcn_cvt_pk_f32_fp8((int)v, false);
#else
  return from_fp8x2((unsigned short)(v & 0xffffu));
#endif
}

__device__ __forceinline__ f32x2 fp8x2_hi(unsigned v) {
#if __has_builtin(__builtin_amdgcn_cvt_pk_f32_fp8)
  return __builtin_amdgcn_cvt_pk_f32_fp8((int)v, true);
#else
  return from_fp8x2((unsigned short)(v >> 16));
#endif
}

// ---------------- bucketed CSR build ----------------

__global__ __launch_bounds__(256) void k_bhist(const int* __restrict__ dst,
                                               int* __restrict__ blockHist,
                                               int* __restrict__ bucketTotal,
                                               int E, int n, int nB) {
  extern __shared__ int hist[];
  for (int i = threadIdx.x; i < nB; i += 256) hist[i] = 0;
  __syncthreads();
  int base = blockIdx.x * EB, end = min(base + EB, E);
  for (int e = base + threadIdx.x; e < end; e += 256) {
    int d = dst[e];
    if ((unsigned)d < (unsigned)n) atomicAdd(&hist[d >> 8], 1);
  }
  __syncthreads();
  for (int i = threadIdx.x; i < nB; i += 256) {
    int v = hist[i];
    blockHist[(long)blockIdx.x * nB + i] = v;
    if (v) atomicAdd(&bucketTotal[i], v);
  }
}

__global__ __launch_bounds__(512) void k_btop(const int* __restrict__ bucketTotal,
                                              int* __restrict__ bucketBase,
                                              int* __restrict__ bucketCursor, int nB) {
  __shared__ int sh[512];
  int t = threadIdx.x;
  int s = (t < nB) ? bucketTotal[t] : 0;
  sh[t] = s;
  __syncthreads();
  for (int off = 1; off < 512; off <<= 1) {
    int v = (t >= off) ? sh[t - off] : 0;
    __syncthreads();
    sh[t] += v;
    __syncthreads();
  }
  if (t < nB) {
    int base = sh[t] - s;
    bucketBase[t] = base;
    bucketCursor[t] = base;
    if (t == nB - 1) bucketBase[nB] = sh[t];
  }
}

__global__ __launch_bounds__(256) void k_bscatter(const int* __restrict__ src,
                                                  const int* __restrict__ dst,
                                                  const int* __restrict__ blockHist,
                                                  int* __restrict__ bucketCursor,
                                                  unsigned* __restrict__ recs,
                                                  int E, int n, int nB) {
  extern __shared__ int cur[];
  for (int i = threadIdx.x; i < nB; i += 256) {
    int c = blockHist[(long)blockIdx.x * nB + i];
    cur[i] = c ? atomicAdd(&bucketCursor[i], c) : 0;
  }
  __syncthreads();
  int base = blockIdx.x * EB, end = min(base + EB, E);
  for (int e = base + threadIdx.x; e < end; e += 256) {
    int d = dst[e];
    if ((unsigned)d < (unsigned)n) {
      int s = min(max(src[e], 0), n - 1);
      int pos = atomicAdd(&cur[d >> 8], 1);
      recs[pos] = ((unsigned)s << 8) | (unsigned)(d & 255);
    }
  }
}

// ---------------- fused bucket fill + layer-1 aggregation ----------------
// Per block = one bucket of 256 nodes: (1) build rowptr slice + col slice
// (global for layer 2, LDS copy for this kernel), (2) aggregate the
// bucket's nodes with R10's quarter-per-node scheme, indices from LDS.

template <bool RELU>
__global__ __launch_bounds__(256) void k_bfill_agg(
    const unsigned* __restrict__ recs, const int* __restrict__ bucketBase,
    int* __restrict__ rowptr, int* __restrict__ col,
    const unsigned char* __restrict__ Y, const __bf16* __restrict__ XR,
    const float* __restrict__ bias, __bf16* __restrict__ out, int n) {
  __shared__ int degl[256];
  __shared__ int incl[256];
  __shared__ int rp[257];
  __shared__ int cur[256];
  __shared__ int colLds[COLCAP];
  int b = blockIdx.x, t = threadIdx.x;
  int rbeg = bucketBase[b], rend = bucketBase[b + 1];
  bool useLds = (rend - rbeg) <= COLCAP;

  degl[t] = 0;
  __syncthreads();
  for (int i = rbeg + t; i < rend; i += 256)
    atomicAdd(&degl[recs[i] & 255], 1);
  __syncthreads();
  incl[t] = degl[t];
  __syncthreads();
  for (int off = 1; off < 256; off <<= 1) {
    int v = (t >= off) ? incl[t - off] : 0;
    __syncthreads();
    incl[t] += v;
    __syncthreads();
  }
  int excl = incl[t] - degl[t];
  rp[t] = rbeg + excl;
  if (t == 255) rp[256] = rend;
  int node = b * 256 + t;
  if (node <= n) rowptr[node] = rbeg + excl;
  cur[t] = rbeg + excl;
  __syncthreads();
  for (int i = rbeg + t; i < rend; i += 256) {
    unsigned r = recs[i];
    int pos = atomicAdd(&cur[r & 255], 1);
    int sv = (int)(r >> 8);
    col[pos] = sv;                              // global (layer-2 agg)
    if (useLds) colLds[pos - rbeg] = sv;        // LDS (this kernel)
  }
  __syncthreads();

  // ---- aggregation: 16 passes x 16 nodes (quarter-per-node) ----
  int wave = t >> 6, lane = t & 63;
  int quarter = lane >> 4, l = lane & 15;
  int sb = lane & 48;
  int co = l * 8;
  const unsigned char* Yc = Y + co;

  for (int pass = 0; pass < 16; ++pass) {
    int nl = pass * 16 + wave * 4 + quarter;  // node-local 0..255
    int nn = b * 256 + nl;
    bool valid = nn < n;
    int beg = rp[nl], end = rp[nl + 1];

    f32x2 av0 = {0.f, 0.f}, av1 = {0.f, 0.f}, av2 = {0.f, 0.f}, av3 = {0.f, 0.f};

    for (int base = beg; base < end; base += 16) {
      int cnt = min(end - base, 16);
      int idx = 0;
      if (l < cnt)
        idx = useLds ? colLds[base - rbeg + l] : col[base + l];
      int j = 0;
      for (; j + 3 < cnt; j += 4) {
        long s0 = (unsigned)__shfl(idx, sb + j);
        long s1 = (unsigned)__shfl(idx, sb + j + 1);
        long s2 = (unsigned)__shfl(idx, sb + j + 2);
        long s3 = (unsigned)__shfl(idx, sb + j + 3);
        uint2 v0 = *(const uint2*)(Yc + s0 * 128);
        uint2 v1 = *(const uint2*)(Yc + s1 * 128);
        uint2 v2 = *(const uint2*)(Yc + s2 * 128);
        uint2 v3 = *(const uint2*)(Yc + s3 * 128);
        av0 += fp8x2_lo(v0.x); av1 += fp8x2_hi(v0.x);
        av2 += fp8x2_lo(v0.y); av3 += fp8x2_hi(v0.y);
        av0 += fp8x2_lo(v1.x); av1 += fp8x2_hi(v1.x);
        av2 += fp8x2_lo(v1.y); av3 += fp8x2_hi(v1.y);
        av0 += fp8x2_lo(v2.x); av1 += fp8x2_hi(v2.x);
        av2 += fp8x2_lo(v2.y); av3 += fp8x2_hi(v2.y);
        av0 += fp8x2_lo(v3.x); av1 += fp8x2_hi(v3.x);
        av2 += fp8x2_lo(v3.y); av3 += fp8x2_hi(v3.y);
      }
      for (; j < cnt; ++j) {
        long s = (unsigned)__shfl(idx, sb + j);
        uint2 v = *(const uint2*)(Yc + s * 128);
        av0 += fp8x2_lo(v.x); av1 += fp8x2_hi(v.x);
        av2 += fp8x2_lo(v.y); av3 += fp8x2_hi(v.y);
      }
    }

    if (valid) {
      float inv = 1.f / (float)max(end - beg, 1);
      bf16x8 xv = *(const bf16x8*)(XR + (long)nn * 128 + co);
      f32x4 b0 = *(const f32x4*)(bias + co);
      f32x4 b1 = *(const f32x4*)(bias + co + 4);
      float r0 = av0[0] * inv + (float)xv[0] + b0[0];
      float r1 = av0[1] * inv + (float)xv[1] + b0[1];
      float r2 = av1[0] * inv + (float)xv[2] + b0[2];
      float r3 = av1[1] * inv + (float)xv[3] + b0[3];
      float r4 = av2[0] * inv + (float)xv[4] + b1[0];
      float r5 = av2[1] * inv + (float)xv[5] + b1[1];
      float r6 = av3[0] * inv + (float)xv[6] + b1[2];
      float r7 = av3[1] * inv + (float)xv[7] + b1[3];
      if (RELU) {
        r0 = fmaxf(r0, 0.f); r1 = fmaxf(r1, 0.f);
        r2 = fmaxf(r2, 0.f); r3 = fmaxf(r3, 0.f);
        r4 = fmaxf(r4, 0.f); r5 = fmaxf(r5, 0.f);
        r6 = fmaxf(r6, 0.f); r7 = fmaxf(r7, 0.f);
      }
      bf16x8 o;
      o[0] = (__bf16)r0; o[1] = (__bf16)r1; o[2] = (__bf16)r2; o[3] = (__bf16)r3;
      o[4] = (__bf16)r4; o[5] = (__bf16)r5; o[6] = (__bf16)r6; o[7] = (__bf16)r7;
      *(bf16x8*)(out + (long)nn * 128 + co) = o;
    }
  }
}

// ---------------- persistent fused-panel GEMM (direct fp32 B) ----------------
// Block = 64-row tiles (grid-stride), 512 threads (8 waves). Wave w:
// panel = w>>2 (Wl->fp8 / Wr->bf16), col strip (w&3)*16*NI, NI=COLS/64.
// B fragments: in-register transposing load from fp32 W + bf16 cast
// (numerically identical to the old wprep path), pinned once per block.
// Double-buffered LDS A with register prefetch of tile t+1.

template <int COLS, typename TIN>
__global__ __launch_bounds__(512, 4) void k_gemm_fused(const TIN* __restrict__ X,
                                                       const float* __restrict__ Wa,
                                                       const float* __restrict__ Wb,
                                                       unsigned char* __restrict__ outA,
                                                       __bf16* __restrict__ outB,
                                                       int nrows, int ntiles) {
  constexpr int LD = 136;
  constexpr int NI = COLS / 64;
  constexpr bool FP32IN = std::is_same_v<TIN, float>;
  __shared__ __bf16 As[2][64 * LD];

  int tid = threadIdx.x;
  int w = tid >> 6, lane = tid & 63;
  int m = lane & 15, quad = lane >> 4;
  int panel = w >> 2;
  int wcol = (w & 3) * (16 * NI);
  const float* Wsrc = panel ? Wb : Wa;

  bf16x8 bq[4][NI];
#pragma unroll
  for (int kc = 0; kc < 4; ++kc)
#pragma unroll
    for (int ni = 0; ni < NI; ++ni)
#pragma unroll
      for (int e = 0; e < 8; ++e)
        bq[kc][ni][e] = (__bf16)Wsrc[(kc * 32 + quad * 8 + e) * COLS + (wcol + ni * 16 + m)];

  float4 ra[4];
  bf16x8 rb[2];

  auto load_tile = [&](int t) {
    long row0 = (long)t * 64;
    if constexpr (FP32IN) {
#pragma unroll
      for (int it = 0; it < 4; ++it) {
        int i = tid + it * 512;
        int r = i >> 5, c4 = (i & 31) << 2;
        long row = row0 + r;
        float4 v = make_float4(0.f, 0.f, 0.f, 0.f);
        if (row < nrows) v = *(const float4*)(X + row * K + c4);
        ra[it] = v;
      }
    } else {
#pragma unroll
      for (int it = 0; it < 2; ++it) {
        int i = tid + it * 512;
        int r = i >> 4, c8 = (i & 15) << 3;
        long row = row0 + r;
        bf16x8 v = {};
        if (row < nrows) v = *(const bf16x8*)(X + row * K + c8);
        rb[it] = v;
      }
    }
  };

  auto write_tile = [&](int buf) {
    if constexpr (FP32IN) {
#pragma unroll
      for (int it = 0; it < 4; ++it) {
        int i = tid + it * 512;
        int r = i >> 5, c4 = (i & 31) << 2;
        bf16x4 bb;
        bb[0] = (__bf16)ra[it].x; bb[1] = (__bf16)ra[it].y;
        bb[2] = (__bf16)ra[it].z; bb[3] = (__bf16)ra[it].w;
        *(bf16x4*)&As[buf][r * LD + c4] = bb;
      }
    } else {
#pragma unroll
      for (int it = 0; it < 2; ++it) {
        int i = tid + it * 512;
        int r = i >> 4, c8 = (i & 15) << 3;
        *(bf16x8*)&As[buf][r * LD + c8] = rb[it];
      }
    }
  };

  int t = (int)blockIdx.x;
  int stride = (int)gridDim.x;
  if (t < ntiles) load_tile(t);

#pragma unroll
  for (int kc = 0; kc < 4; ++kc)
#pragma unroll
    for (int ni = 0; ni < NI; ++ni)
      asm volatile("" :: "v"(bq[kc][ni]));

  int buf = 0;
  while (t < ntiles) {
    write_tile(buf);
    __syncthreads();
    int tn = t + stride;
    if (tn < ntiles) load_tile(tn);  // prefetch under compute

    f32x4 acc[4][NI];
#pragma unroll
    for (int mi = 0; mi < 4; ++mi)
#pragma unroll
      for (int ni = 0; ni < NI; ++ni) acc[mi][ni] = (f32x4){0.f, 0.f, 0.f, 0.f};

#pragma unroll
    for (int kc = 0; kc < 4; ++kc) {
      int ko = kc * 32 + quad * 8;
      bf16x8 af[4];
#pragma unroll
      for (int mi = 0; mi < 4; ++mi)
        af[mi] = *(const bf16x8*)&As[buf][(mi * 16 + m) * LD + ko];
#pragma unroll
      for (int mi = 0; mi < 4; ++mi)
#pragma unroll
        for (int ni = 0; ni < NI; ++ni)
          acc[mi][ni] = __builtin_amdgcn_mfma_f32_16x16x32_bf16(af[mi], bq[kc][ni], acc[mi][ni], 0, 0, 0);
    }

    long row0 = (long)t * 64;
#pragma unroll
    for (int mi = 0; mi < 4; ++mi) {
#pragma unroll
      for (int r = 0; r < 4; ++r) {
        long grow = row0 + mi * 16 + quad * 4 + r;
        if (grow < nrows) {
#pragma unroll
          for (int ni = 0; ni < NI; ++ni) {
            long idx = grow * COLS + wcol + ni * 16 + m;
            float v = acc[mi][ni][r];
            if (panel == 0) outA[idx] = to_fp8(v);
            else            outB[idx] = (__bf16)v;
          }
        }
      }
    }
    t = tn;
    buf ^= 1;
  }
}

// ---------------- layer-2 aggregation (unchanged R10 structure) ----------------

__global__ __launch_bounds__(256) void k_agg64(const unsigned char* __restrict__ Y,
                                               const __bf16* __restrict__ XR,
                                               const float* __restrict__ bias,
                                               const int* __restrict__ rowptr,
                                               const int* __restrict__ col,
                                               float* __restrict__ out, int nnodes) {
  int wave = threadIdx.x >> 6, lane = threadIdx.x & 63;
  int quarter = lane >> 4, l = lane & 15;
  int sb = lane & 48;
  int n = blockIdx.x * 16 + wave * 4 + quarter;
  bool valid = n < nnodes;
  int beg = 0, end = 0;
  if (valid) {
    beg = rowptr[n];
    end = rowptr[n + 1];
  }
  int co = l * 4;
  const unsigned char* Yc = Y + co;

  f32x2 av0 = {0.f, 0.f}, av1 = {0.f, 0.f};

  for (int base = beg; base < end; base += 16) {
    int cnt = min(end - base, 16);
    int idx = (l < cnt) ? col[base + l] : 0;
    int j = 0;
    for (; j + 3 < cnt; j += 4) {
      long s0 = (unsigned)__shfl(idx, sb + j);
      long s1 = (unsigned)__shfl(idx, sb + j + 1);
      long s2 = (unsigned)__shfl(idx, sb + j + 2);
      long s3 = (unsigned)__shfl(idx, sb + j + 3);
      unsigned v0 = *(const unsigned*)(Yc + s0 * 64);
      unsigned v1 = *(const unsigned*)(Yc + s1 * 64);
      unsigned v2 = *(const unsigned*)(Yc + s2 * 64);
      unsigned v3 = *(const unsigned*)(Yc + s3 * 64);
      av0 += fp8x2_lo(v0); av1 += fp8x2_hi(v0);
      av0 += fp8x2_lo(v1); av1 += fp8x2_hi(v1);
      av0 += fp8x2_lo(v2); av1 += fp8x2_hi(v2);
      av0 += fp8x2_lo(v3); av1 += fp8x2_hi(v3);
    }
    for (; j < cnt; ++j) {
      long s = (unsigned)__shfl(idx, sb + j);
      unsigned v = *(const unsigned*)(Yc + s * 64);
      av0 += fp8x2_lo(v); av1 += fp8x2_hi(v);
    }
  }

  if (valid) {
    float inv = 1.f / (float)max(end - beg, 1);
    bf16x4 xv = *(const bf16x4*)(XR + (long)n * 64 + co);
    f32x4 bv = *(const f32x4*)(bias + co);
    f32x4 r;
    r[0] = av0[0] * inv + (float)xv[0] + bv[0];
    r[1] = av0[1] * inv + (float)xv[1] + bv[1];
    r[2] = av1[0] * inv + (float)xv[2] + bv[2];
    r[3] = av1[1] * inv + (float)xv[3] + bv[3];
    *(f32x4*)(out + (long)n * 64 + co) = r;
  }
}

// ---------------- launch ----------------

extern "C" void kernel_launch(void* const* d_in, const int* in_sizes, int n_in,
                              void* d_out, int out_size, void* d_ws, size_t ws_size,
                              hipStream_t stream) {
  const float* x   = (const float*)d_in[0];
  const int*   ei  = (const int*)d_in[1];
  const float* W1l = (const float*)d_in[2];
  const float* W1r = (const float*)d_in[3];
  const float* b1  = (const float*)d_in[4];
  const float* W2l = (const float*)d_in[5];
  const float* W2r = (const float*)d_in[6];
  const float* b2  = (const float*)d_in[7];
  float* out = (float*)d_out;

  int N = in_sizes[0] / K;   // 100000
  int E = in_sizes[1] / 2;   // 1600000
  const int* src = ei;
  const int* dst = ei + E;

  int nB = (N + 255) >> 8;          // 391 buckets of 256 nodes
  int nblk = (E + EB - 1) / EB;     // 391 partition blocks

  char* ws = (char*)d_ws;
  size_t off = 0;
  auto alloc = [&](size_t bytes) {
    void* p = ws + off;
    off = (off + bytes + 255) & ~(size_t)255;
    return p;
  };
  int*      rowptr       = (int*)alloc(((size_t)N + 2) * 4);
  int*      col          = (int*)alloc((size_t)E * 4);
  int*      blockHist    = (int*)alloc((size_t)nblk * nB * 4);
  int*      bucketTotal  = (int*)alloc((size_t)nB * 4);
  int*      bucketBase   = (int*)alloc(((size_t)nB + 1) * 4);
  int*      bucketCursor = (int*)alloc((size_t)nB * 4);
  unsigned* recs         = (unsigned*)alloc((size_t)E * 4);
  unsigned char* y1      = (unsigned char*)alloc((size_t)N * 128);  // fp8
  __bf16*   xr           = (__bf16*)alloc((size_t)N * 128 * 2);
  __bf16*   h            = (__bf16*)alloc((size_t)N * 128 * 2);
  unsigned char* y2 = y1;  // layer-1 gather buffer dead after bfill_agg; reuse
  __bf16*   hr = xr;

  int ntiles = (N + 63) / 64;
  int gpers = ntiles < 512 ? ntiles : 512;

  // CSR build (memset + atomic bucketTotal: proven-fast path)
  hipMemsetAsync(bucketTotal, 0, (size_t)nB * 4, stream);
  k_bhist<<<nblk, 256, nB * 4, stream>>>(dst, blockHist, bucketTotal, E, N, nB);
  k_btop<<<1, 512, 0, stream>>>(bucketTotal, bucketBase, bucketCursor, nB);
  k_bscatter<<<nblk, 256, nB * 4, stream>>>(src, dst, blockHist, bucketCursor, recs, E, N, nB);

  // layer 1: y1 = fp8(x@W1l), xr = bf16(x@W1r)
  k_gemm_fused<128, float><<<gpers, 512, 0, stream>>>(x, W1l, W1r, y1, xr, N, ntiles);

  // fused: fill rowptr/col per bucket + h = relu(mean(y1) + xr + b1)
  k_bfill_agg<true><<<nB, 256, 0, stream>>>(recs, bucketBase, rowptr, col, y1, xr, b1, h, N);

  // layer 2: y2 = fp8(h@W2l), hr = bf16(h@W2r)
  k_gemm_fused<64, __bf16><<<gpers, 512, 0, stream>>>(h, W2l, W2r, y2, hr, N, ntiles);

  // out = mean_gather(y2) + hr + b2
  k_agg64<<<(N + 15) / 16, 256, 0, stream>>>(y2, hr, b2, rowptr, col, out, N);
}

// Round 11
// 245.748 us; speedup vs baseline: 1.5458x; 1.2108x over previous
//
#include <hip/hip_runtime.h>
#include <type_traits>

// GraphSAGE 2-layer, N=100k, C 128->128->64, E=1.6M, fp32 in/out.
// R9/R10: latency-optimized quarter-per-node aggregation.
// R11-R15: fused-panel persistent GEMM — 266us baseline.
// R16: cooperative mega-kernel FAILED (coop launch vs graph capture).
// R17: wprep deleted (direct fp32-B load) — VALIDATED; btop-column-sum
//      REGRESSED (98us).
// R18: bfill+agg128 fusion REGRESSED (93us: 391-block grid = 1.5 blk/CU,
//      machine idle). memset+atomic btop path restored — VALIDATED.
// R19: unfuse bfill/agg128 (back to proven 391/6250-block split); merge
//      bhist+bscatter into ONE k_scatter with slotted recs layout
//      (recs[bucket*CAP+i], LDS hist -> range reserve -> LDS-cursor
//      scatter). 8 dispatches, no blockHist round-trip.

constexpr int K = 128;
constexpr int EB = 4096;     // edges per partition block
constexpr int CAP = 8192;    // slots per bucket (mean 4092, +64 sigma)

typedef __bf16 bf16x2 __attribute__((ext_vector_type(2)));
typedef __bf16 bf16x4 __attribute__((ext_vector_type(4)));
typedef __bf16 bf16x8 __attribute__((ext_vector_type(8)));
typedef float f32x4 __attribute__((ext_vector_type(4)));
typedef float f32x2 __attribute__((ext_vector_type(2)));

// ---------------- fp8 e4m3 conversion ----------------

__device__ __forceinline__ unsigned char to_fp8(float v) {
#if __has_builtin(__builtin_amdgcn_cvt_pk_fp8_f32)
  int p = __builtin_amdgcn_cvt_pk_fp8_f32(v, v, 0, false);
  return (unsigned char)(p & 0xff);
#else
  unsigned u = __builtin_bit_cast(unsigned, v);
  unsigned s = (u >> 24) & 0x80u;
  float a = fabsf(v);
  if (a > 448.f) a = 448.f;
  unsigned bits;
  if (a < 0.015625f) {
    bits = (unsigned)(a * 512.f + 0.5f);
  } else {
    unsigned b = __builtin_bit_cast(unsigned, a);
    b += ((b >> 20) & 1) + 0x0007FFFF;
    unsigned e = (b >> 23) - 120;
    bits = (e << 3) | ((b >> 20) & 7);
    if (bits > 0x7E) bits = 0x7E;
  }
  return (unsigned char)(s | bits);
#endif
}

__device__ __forceinline__ f32x2 from_fp8x2(unsigned short u) {
#if __has_builtin(__builtin_amdgcn_cvt_pk_f32_fp8)
  return __builtin_amdgcn_cvt_pk_f32_fp8((int)u, false);
#else
  f32x2 r;
  unsigned b0 = u & 0xff, b1 = (u >> 8) & 0xff;
  unsigned e0 = (b0 >> 3) & 15, m0 = b0 & 7;
  unsigned e1 = (b1 >> 3) & 15, m1 = b1 & 7;
  float v0 = e0 ? __builtin_bit_cast(float, ((e0 + 120) << 23) | (m0 << 20))
              : (float)m0 * 0.001953125f;
  float v1 = e1 ? __builtin_bit_cast(float, ((e1 + 120) << 23) | (m1 << 20))
              : (float)m1 * 0.001953125f;
  r[0] = (b0 & 0x80) ? -v0 : v0;
  r[1] = (b1 & 0x80) ? -v1 : v1;
  return r;
#endif
}

__device__ __forceinline__ f32x2 fp8x2_lo(unsigned v) {
#if __has_builtin(__builtin_amdgcn_cvt_pk_f32_fp8)
  return __builtin_amdgcn_cvt_pk_f32_fp8((int)v, false);
#else
  return from_fp8x2((unsigned short)(v & 0xffffu));
#endif
}

__device__ __forceinline__ f32x2 fp8x2_hi(unsigned v) {
#if __has_builtin(__builtin_amdgcn_cvt_pk_f32_fp8)
  return __builtin_amdgcn_cvt_pk_f32_fp8((int)v, true);
#else
  return from_fp8x2((unsigned short)(v >> 16));
#endif
}

// ---------------- single-pass bucketed scatter (slotted layout) ----------------
// Per block: LDS hist of its edge range -> reserve a contiguous range in
// each touched bucket via ONE global atomicAdd -> LDS-cursor scatter into
// recs[bucket*CAP + slot]. No blockHist global round-trip.

__global__ __launch_bounds__(256) void k_scatter(const int* __restrict__ src,
                                                 const int* __restrict__ dst,
                                                 int* __restrict__ bucketCount,
                                                 unsigned* __restrict__ recs,
                                                 int E, int n, int nB) {
  extern __shared__ int cur[];
  for (int i = threadIdx.x; i < nB; i += 256) cur[i] = 0;
  __syncthreads();
  int base = blockIdx.x * EB, end = min(base + EB, E);
  for (int e = base + threadIdx.x; e < end; e += 256) {
    int d = dst[e];
    if ((unsigned)d < (unsigned)n) atomicAdd(&cur[d >> 8], 1);
  }
  __syncthreads();
  for (int i = threadIdx.x; i < nB; i += 256) {
    int c = cur[i];
    cur[i] = c ? atomicAdd(&bucketCount[i], c) : 0;
  }
  __syncthreads();
  for (int e = base + threadIdx.x; e < end; e += 256) {
    int d = dst[e];
    if ((unsigned)d < (unsigned)n) {
      int s = min(max(src[e], 0), n - 1);
      int b = d >> 8;
      int pos = min(atomicAdd(&cur[b], 1), CAP - 1);  // clamp: OOB-safe
      recs[(long)b * CAP + pos] = ((unsigned)s << 8) | (unsigned)(d & 255);
    }
  }
}

// Exclusive scan of bucketCount -> bucketBase (global col/rowptr offsets).
__global__ __launch_bounds__(512) void k_btop(const int* __restrict__ bucketCount,
                                              int* __restrict__ bucketBase, int nB) {
  __shared__ int sh[512];
  int t = threadIdx.x;
  int s = (t < nB) ? bucketCount[t] : 0;
  sh[t] = s;
  __syncthreads();
  for (int off = 1; off < 512; off <<= 1) {
    int v = (t >= off) ? sh[t - off] : 0;
    __syncthreads();
    sh[t] += v;
    __syncthreads();
  }
  if (t < nB) {
    bucketBase[t] = sh[t] - s;
    if (t == nB - 1) bucketBase[nB] = sh[t];
  }
}

// Per-bucket rowptr + col fill from the slotted recs region (proven R15
// structure, adapted to slotted input).
__global__ __launch_bounds__(256) void k_bfill(const unsigned* __restrict__ recs,
                                               const int* __restrict__ bucketBase,
                                               const int* __restrict__ bucketCount,
                                               int* __restrict__ rowptr,
                                               int* __restrict__ col, int n) {
  __shared__ int degl[256];
  __shared__ int incl[256];
  int b = blockIdx.x, t = threadIdx.x;
  int rbeg = bucketBase[b];
  int cnt = bucketCount[b];
  const unsigned* rbase = recs + (long)b * CAP;
  degl[t] = 0;
  __syncthreads();
  for (int i = t; i < cnt; i += 256)
    atomicAdd(&degl[rbase[i] & 255], 1);
  __syncthreads();
  incl[t] = degl[t];
  __syncthreads();
  for (int off = 1; off < 256; off <<= 1) {
    int v = (t >= off) ? incl[t - off] : 0;
    __syncthreads();
    incl[t] += v;
    __syncthreads();
  }
  int excl = incl[t] - degl[t];
  int node = b * 256 + t;
  if (node <= n) rowptr[node] = rbeg + excl;
  __syncthreads();
  degl[t] = rbeg + excl;  // reuse as cursor
  __syncthreads();
  for (int i = t; i < cnt; i += 256) {
    unsigned r = rbase[i];
    int pos = atomicAdd(&degl[r & 255], 1);
    col[pos] = (int)(r >> 8);
  }
}

// ---------------- persistent fused-panel GEMM (direct fp32 B) ----------------
// Block = 64-row tiles (grid-stride), 512 threads (8 waves). Wave w:
// panel = w>>2 (Wl->fp8 / Wr->bf16), col strip (w&3)*16*NI, NI=COLS/64.
// B fragments: in-register transposing load from fp32 W + bf16 cast
// (numerically identical to the old wprep path), pinned once per block.
// Double-buffered LDS A with register prefetch of tile t+1.

template <int COLS, typename TIN>
__global__ __launch_bounds__(512, 4) void k_gemm_fused(const TIN* __restrict__ X,
                                                       const float* __restrict__ Wa,
                                                       const float* __restrict__ Wb,
                                                       unsigned char* __restrict__ outA,
                                                       __bf16* __restrict__ outB,
                                                       int nrows, int ntiles) {
  constexpr int LD = 136;
  constexpr int NI = COLS / 64;
  constexpr bool FP32IN = std::is_same_v<TIN, float>;
  __shared__ __bf16 As[2][64 * LD];

  int tid = threadIdx.x;
  int w = tid >> 6, lane = tid & 63;
  int m = lane & 15, quad = lane >> 4;
  int panel = w >> 2;
  int wcol = (w & 3) * (16 * NI);
  const float* Wsrc = panel ? Wb : Wa;

  bf16x8 bq[4][NI];
#pragma unroll
  for (int kc = 0; kc < 4; ++kc)
#pragma unroll
    for (int ni = 0; ni < NI; ++ni)
#pragma unroll
      for (int e = 0; e < 8; ++e)
        bq[kc][ni][e] = (__bf16)Wsrc[(kc * 32 + quad * 8 + e) * COLS + (wcol + ni * 16 + m)];

  float4 ra[4];
  bf16x8 rb[2];

  auto load_tile = [&](int t) {
    long row0 = (long)t * 64;
    if constexpr (FP32IN) {
#pragma unroll
      for (int it = 0; it < 4; ++it) {
        int i = tid + it * 512;
        int r = i >> 5, c4 = (i & 31) << 2;
        long row = row0 + r;
        float4 v = make_float4(0.f, 0.f, 0.f, 0.f);
        if (row < nrows) v = *(const float4*)(X + row * K + c4);
        ra[it] = v;
      }
    } else {
#pragma unroll
      for (int it = 0; it < 2; ++it) {
        int i = tid + it * 512;
        int r = i >> 4, c8 = (i & 15) << 3;
        long row = row0 + r;
        bf16x8 v = {};
        if (row < nrows) v = *(const bf16x8*)(X + row * K + c8);
        rb[it] = v;
      }
    }
  };

  auto write_tile = [&](int buf) {
    if constexpr (FP32IN) {
#pragma unroll
      for (int it = 0; it < 4; ++it) {
        int i = tid + it * 512;
        int r = i >> 5, c4 = (i & 31) << 2;
        bf16x4 bb;
        bb[0] = (__bf16)ra[it].x; bb[1] = (__bf16)ra[it].y;
        bb[2] = (__bf16)ra[it].z; bb[3] = (__bf16)ra[it].w;
        *(bf16x4*)&As[buf][r * LD + c4] = bb;
      }
    } else {
#pragma unroll
      for (int it = 0; it < 2; ++it) {
        int i = tid + it * 512;
        int r = i >> 4, c8 = (i & 15) << 3;
        *(bf16x8*)&As[buf][r * LD + c8] = rb[it];
      }
    }
  };

  int t = (int)blockIdx.x;
  int stride = (int)gridDim.x;
  if (t < ntiles) load_tile(t);

#pragma unroll
  for (int kc = 0; kc < 4; ++kc)
#pragma unroll
    for (int ni = 0; ni < NI; ++ni)
      asm volatile("" :: "v"(bq[kc][ni]));

  int buf = 0;
  while (t < ntiles) {
    write_tile(buf);
    __syncthreads();
    int tn = t + stride;
    if (tn < ntiles) load_tile(tn);  // prefetch under compute

    f32x4 acc[4][NI];
#pragma unroll
    for (int mi = 0; mi < 4; ++mi)
#pragma unroll
      for (int ni = 0; ni < NI; ++ni) acc[mi][ni] = (f32x4){0.f, 0.f, 0.f, 0.f};

#pragma unroll
    for (int kc = 0; kc < 4; ++kc) {
      int ko = kc * 32 + quad * 8;
      bf16x8 af[4];
#pragma unroll
      for (int mi = 0; mi < 4; ++mi)
        af[mi] = *(const bf16x8*)&As[buf][(mi * 16 + m) * LD + ko];
#pragma unroll
      for (int mi = 0; mi < 4; ++mi)
#pragma unroll
        for (int ni = 0; ni < NI; ++ni)
          acc[mi][ni] = __builtin_amdgcn_mfma_f32_16x16x32_bf16(af[mi], bq[kc][ni], acc[mi][ni], 0, 0, 0);
    }

    long row0 = (long)t * 64;
#pragma unroll
    for (int mi = 0; mi < 4; ++mi) {
#pragma unroll
      for (int r = 0; r < 4; ++r) {
        long grow = row0 + mi * 16 + quad * 4 + r;
        if (grow < nrows) {
#pragma unroll
          for (int ni = 0; ni < NI; ++ni) {
            long idx = grow * COLS + wcol + ni * 16 + m;
            float v = acc[mi][ni][r];
            if (panel == 0) outA[idx] = to_fp8(v);
            else            outB[idx] = (__bf16)v;
          }
        }
      }
    }
    t = tn;
    buf ^= 1;
  }
}

// ---------------- aggregation (proven R10 structure, full grids) ----------------

template <bool RELU>
__global__ __launch_bounds__(256) void k_agg128(const unsigned char* __restrict__ Y,
                                                const __bf16* __restrict__ XR,
                                                const float* __restrict__ bias,
                                                const int* __restrict__ rowptr,
                                                const int* __restrict__ col,
                                                __bf16* __restrict__ out, int nnodes) {
  int wave = threadIdx.x >> 6, lane = threadIdx.x & 63;
  int quarter = lane >> 4, l = lane & 15;
  int sb = lane & 48;
  int n = blockIdx.x * 16 + wave * 4 + quarter;
  bool valid = n < nnodes;
  int beg = 0, end = 0;
  if (valid) {
    beg = rowptr[n];
    end = rowptr[n + 1];
  }
  int co = l * 8;
  const unsigned char* Yc = Y + co;

  f32x2 av0 = {0.f, 0.f}, av1 = {0.f, 0.f}, av2 = {0.f, 0.f}, av3 = {0.f, 0.f};

  for (int base = beg; base < end; base += 16) {
    int cnt = min(end - base, 16);
    int idx = (l < cnt) ? col[base + l] : 0;
    int j = 0;
    for (; j + 3 < cnt; j += 4) {
      long s0 = (unsigned)__shfl(idx, sb + j);
      long s1 = (unsigned)__shfl(idx, sb + j + 1);
      long s2 = (unsigned)__shfl(idx, sb + j + 2);
      long s3 = (unsigned)__shfl(idx, sb + j + 3);
      uint2 v0 = *(const uint2*)(Yc + s0 * 128);
      uint2 v1 = *(const uint2*)(Yc + s1 * 128);
      uint2 v2 = *(const uint2*)(Yc + s2 * 128);
      uint2 v3 = *(const uint2*)(Yc + s3 * 128);
      av0 += fp8x2_lo(v0.x); av1 += fp8x2_hi(v0.x);
      av2 += fp8x2_lo(v0.y); av3 += fp8x2_hi(v0.y);
      av0 += fp8x2_lo(v1.x); av1 += fp8x2_hi(v1.x);
      av2 += fp8x2_lo(v1.y); av3 += fp8x2_hi(v1.y);
      av0 += fp8x2_lo(v2.x); av1 += fp8x2_hi(v2.x);
      av2 += fp8x2_lo(v2.y); av3 += fp8x2_hi(v2.y);
      av0 += fp8x2_lo(v3.x); av1 += fp8x2_hi(v3.x);
      av2 += fp8x2_lo(v3.y); av3 += fp8x2_hi(v3.y);
    }
    for (; j < cnt; ++j) {
      long s = (unsigned)__shfl(idx, sb + j);
      uint2 v = *(const uint2*)(Yc + s * 128);
      av0 += fp8x2_lo(v.x); av1 += fp8x2_hi(v.x);
      av2 += fp8x2_lo(v.y); av3 += fp8x2_hi(v.y);
    }
  }

  if (valid) {
    float inv = 1.f / (float)max(end - beg, 1);
    bf16x8 xv = *(const bf16x8*)(XR + (long)n * 128 + co);
    f32x4 b0 = *(const f32x4*)(bias + co);
    f32x4 b1 = *(const f32x4*)(bias + co + 4);
    float r0 = av0[0] * inv + (float)xv[0] + b0[0];
    float r1 = av0[1] * inv + (float)xv[1] + b0[1];
    float r2 = av1[0] * inv + (float)xv[2] + b0[2];
    float r3 = av1[1] * inv + (float)xv[3] + b0[3];
    float r4 = av2[0] * inv + (float)xv[4] + b1[0];
    float r5 = av2[1] * inv + (float)xv[5] + b1[1];
    float r6 = av3[0] * inv + (float)xv[6] + b1[2];
    float r7 = av3[1] * inv + (float)xv[7] + b1[3];
    if (RELU) {
      r0 = fmaxf(r0, 0.f); r1 = fmaxf(r1, 0.f);
      r2 = fmaxf(r2, 0.f); r3 = fmaxf(r3, 0.f);
      r4 = fmaxf(r4, 0.f); r5 = fmaxf(r5, 0.f);
      r6 = fmaxf(r6, 0.f); r7 = fmaxf(r7, 0.f);
    }
    bf16x8 o;
    o[0] = (__bf16)r0; o[1] = (__bf16)r1; o[2] = (__bf16)r2; o[3] = (__bf16)r3;
    o[4] = (__bf16)r4; o[5] = (__bf16)r5; o[6] = (__bf16)r6; o[7] = (__bf16)r7;
    *(bf16x8*)(out + (long)n * 128 + co) = o;
  }
}

__global__ __launch_bounds__(256) void k_agg64(const unsigned char* __restrict__ Y,
                                               const __bf16* __restrict__ XR,
                                               const float* __restrict__ bias,
                                               const int* __restrict__ rowptr,
                                               const int* __restrict__ col,
                                               float* __restrict__ out, int nnodes) {
  int wave = threadIdx.x >> 6, lane = threadIdx.x & 63;
  int quarter = lane >> 4, l = lane & 15;
  int sb = lane & 48;
  int n = blockIdx.x * 16 + wave * 4 + quarter;
  bool valid = n < nnodes;
  int beg = 0, end = 0;
  if (valid) {
    beg = rowptr[n];
    end = rowptr[n + 1];
  }
  int co = l * 4;
  const unsigned char* Yc = Y + co;

  f32x2 av0 = {0.f, 0.f}, av1 = {0.f, 0.f};

  for (int base = beg; base < end; base += 16) {
    int cnt = min(end - base, 16);
    int idx = (l < cnt) ? col[base + l] : 0;
    int j = 0;
    for (; j + 3 < cnt; j += 4) {
      long s0 = (unsigned)__shfl(idx, sb + j);
      long s1 = (unsigned)__shfl(idx, sb + j + 1);
      long s2 = (unsigned)__shfl(idx, sb + j + 2);
      long s3 = (unsigned)__shfl(idx, sb + j + 3);
      unsigned v0 = *(const unsigned*)(Yc + s0 * 64);
      unsigned v1 = *(const unsigned*)(Yc + s1 * 64);
      unsigned v2 = *(const unsigned*)(Yc + s2 * 64);
      unsigned v3 = *(const unsigned*)(Yc + s3 * 64);
      av0 += fp8x2_lo(v0); av1 += fp8x2_hi(v0);
      av0 += fp8x2_lo(v1); av1 += fp8x2_hi(v1);
      av0 += fp8x2_lo(v2); av1 += fp8x2_hi(v2);
      av0 += fp8x2_lo(v3); av1 += fp8x2_hi(v3);
    }
    for (; j < cnt; ++j) {
      long s = (unsigned)__shfl(idx, sb + j);
      unsigned v = *(const unsigned*)(Yc + s * 64);
      av0 += fp8x2_lo(v); av1 += fp8x2_hi(v);
    }
  }

  if (valid) {
    float inv = 1.f / (float)max(end - beg, 1);
    bf16x4 xv = *(const bf16x4*)(XR + (long)n * 64 + co);
    f32x4 bv = *(const f32x4*)(bias + co);
    f32x4 r;
    r[0] = av0[0] * inv + (float)xv[0] + bv[0];
    r[1] = av0[1] * inv + (float)xv[1] + bv[1];
    r[2] = av1[0] * inv + (float)xv[2] + bv[2];
    r[3] = av1[1] * inv + (float)xv[3] + bv[3];
    *(f32x4*)(out + (long)n * 64 + co) = r;
  }
}

// ---------------- launch ----------------

extern "C" void kernel_launch(void* const* d_in, const int* in_sizes, int n_in,
                              void* d_out, int out_size, void* d_ws, size_t ws_size,
                              hipStream_t stream) {
  const float* x   = (const float*)d_in[0];
  const int*   ei  = (const int*)d_in[1];
  const float* W1l = (const float*)d_in[2];
  const float* W1r = (const float*)d_in[3];
  const float* b1  = (const float*)d_in[4];
  const float* W2l = (const float*)d_in[5];
  const float* W2r = (const float*)d_in[6];
  const float* b2  = (const float*)d_in[7];
  float* out = (float*)d_out;

  int N = in_sizes[0] / K;   // 100000
  int E = in_sizes[1] / 2;   // 1600000
  const int* src = ei;
  const int* dst = ei + E;

  int nB = (N + 255) >> 8;          // 391 buckets of 256 nodes
  int nblk = (E + EB - 1) / EB;     // 391 partition blocks

  char* ws = (char*)d_ws;
  size_t off = 0;
  auto alloc = [&](size_t bytes) {
    void* p = ws + off;
    off = (off + bytes + 255) & ~(size_t)255;
    return p;
  };
  int*      rowptr      = (int*)alloc(((size_t)N + 2) * 4);
  int*      col         = (int*)alloc((size_t)E * 4);
  int*      bucketCount = (int*)alloc((size_t)nB * 4);
  int*      bucketBase  = (int*)alloc(((size_t)nB + 1) * 4);
  unsigned* recs        = (unsigned*)alloc((size_t)nB * CAP * 4);
  unsigned char* y1     = (unsigned char*)alloc((size_t)N * 128);  // fp8
  __bf16*   xr          = (__bf16*)alloc((size_t)N * 128 * 2);
  __bf16*   h           = (__bf16*)alloc((size_t)N * 128 * 2);
  unsigned char* y2 = y1;  // layer-1 gather buffer dead after agg128; reuse
  __bf16*   hr = xr;

  int ntiles = (N + 63) / 64;
  int gpers = ntiles < 512 ? ntiles : 512;

  // CSR build: single-pass slotted scatter + scan
  hipMemsetAsync(bucketCount, 0, (size_t)nB * 4, stream);
  k_scatter<<<nblk, 256, nB * 4, stream>>>(src, dst, bucketCount, recs, E, N, nB);
  k_btop<<<1, 512, 0, stream>>>(bucketCount, bucketBase, nB);

  // layer 1: y1 = fp8(x@W1l), xr = bf16(x@W1r)
  k_gemm_fused<128, float><<<gpers, 512, 0, stream>>>(x, W1l, W1r, y1, xr, N, ntiles);

  // rowptr/col fill (391 blocks), then aggregation (6250 blocks)
  k_bfill<<<nB, 256, 0, stream>>>(recs, bucketBase, bucketCount, rowptr, col, N);
  k_agg128<true><<<(N + 15) / 16, 256, 0, stream>>>(y1, xr, b1, rowptr, col, h, N);

  // layer 2: y2 = fp8(h@W2l), hr = bf16(h@W2r)
  k_gemm_fused<64, __bf16><<<gpers, 512, 0, stream>>>(h, W2l, W2r, y2, hr, N, ntiles);

  // out = mean_gather(y2) + hr + b2
  k_agg64<<<(N + 15) / 16, 256, 0, stream>>>(y2, hr, b2, rowptr, col, out, N);
}